// Round 9
// baseline (689.984 us; speedup 1.0000x reference)
//
#include <hip/hip_runtime.h>
#include <math.h>

#define BB 4
#define NN 32768
#define CC 512
#define MM 512
#define CAP 8192
#define TPB 512
#define KPT (CAP / TPB)    // 16 slots per thread
#define NPAIR (KPT / 2)

typedef float f32x2 __attribute__((ext_vector_type(2)));
typedef unsigned long long u64;

// ---- workspace layout (bytes) ----
#define OFF_G      0
#define OFF_MASK   (OFF_G + BB*NN*4)           // graspness f32
#define OFF_CNT    (OFF_MASK + BB*NN)          // mask u8
#define OFF_CIDX   (OFF_CNT + 256)             // cnt ints (padded)
#define OFF_CXYZD  (OFF_CIDX + BB*CAP*4)       // compacted orig indices
#define OFF_IDXSEL (OFF_CXYZD + BB*CAP*16)     // compacted float4 {x,y,z, idx_bits}
#define OFF_DSLOW  (OFF_IDXSEL + BB*MM*4)      // slow-path dist array
// total = OFF_DSLOW + BB*NN*4 ~= 1.85 MB

// ---------------- kernel 1: scoring heads + mask ----------------
__global__ __launch_bounds__(256) void k_score(const float* __restrict__ feat,
                                               const float* __restrict__ Wobj,
                                               const float* __restrict__ bobj,
                                               const float* __restrict__ Wg,
                                               const float* __restrict__ bg,
                                               float* __restrict__ g_out,
                                               unsigned char* __restrict__ mask_out) {
    __shared__ float w0[CC], w1[CC], wg[CC];
    for (int c = threadIdx.x; c < CC; c += 256) {
        w0[c] = Wobj[c];
        w1[c] = Wobj[CC + c];
        wg[c] = Wg[c];
    }
    __syncthreads();
    int b = blockIdx.y;
    int n = blockIdx.x * 256 + threadIdx.x;
    const float* f = feat + (size_t)b * CC * NN + n;
    double a0 = 0.0, a1 = 0.0, ag = 0.0;
#pragma unroll 8
    for (int c = 0; c < CC; c++) {
        double fv = (double)f[(size_t)c * NN];
        a0 += fv * (double)w0[c];
        a1 += fv * (double)w1[c];
        ag += fv * (double)wg[c];
    }
    float o0 = (float)(a0 + (double)bobj[0]);
    float o1 = (float)(a1 + (double)bobj[1]);
    float g  = (float)(ag + (double)bg[0]);
    g_out[b * NN + n] = g;
    // argmax([o0,o1])==1 requires strict o1>o0 (argmax picks first max)
    mask_out[b * NN + n] = (o1 > o0 && g > 0.1f) ? 1 : 0;
}

// ---------------- kernel 2: stable compaction of masked points ----------------
__global__ __launch_bounds__(1024) void k_compact(const float* __restrict__ pc,
                                                  const unsigned char* __restrict__ mask,
                                                  int* __restrict__ cnt,
                                                  int* __restrict__ cidx,
                                                  float4* __restrict__ cxyzd) {
    int b = blockIdx.x, tid = threadIdx.x;
    int lane = tid & 63, wv = tid >> 6;
    __shared__ int wcnt[16], woff[16];
    __shared__ int base;
    if (tid == 0) base = 0;
    __syncthreads();
    for (int ch = 0; ch < NN / 1024; ch++) {
        int n = ch * 1024 + tid;
        bool m = mask[(size_t)b * NN + n] != 0;
        unsigned long long bal = __ballot(m);
        int before = __popcll(bal & ((1ull << lane) - 1ull));
        if (lane == 0) wcnt[wv] = __popcll(bal);
        __syncthreads();
        if (tid == 0) {
            int r = base;
            for (int w = 0; w < 16; w++) { woff[w] = r; r += wcnt[w]; }
            base = r;
        }
        __syncthreads();
        if (m) {
            int pos = woff[wv] + before;
            if (pos < CAP) {
                cidx[b * CAP + pos] = n;
                const float* p = pc + ((size_t)b * NN + n) * 3;
                cxyzd[b * CAP + pos] = make_float4(p[0], p[1], p[2], __int_as_float(n));
            }
        }
        __syncthreads();
    }
    if (tid == 0) cnt[b] = base;
}

// ---- u64-key DPP pair-max (builtin form: compiler inserts DPP hazard nops) ----
template<int CTRL, int RMASK>
__device__ __forceinline__ void dpp_key_max(u64& key) {
    int lo = (int)(unsigned)key;
    int hi = (int)(unsigned)(key >> 32);
    int olo = __builtin_amdgcn_update_dpp(lo, lo, CTRL, RMASK, 0xF, false);
    int ohi = __builtin_amdgcn_update_dpp(hi, hi, CTRL, RMASK, 0xF, false);
    u64 okey = ((u64)(unsigned)ohi << 32) | (unsigned)olo;
    if (okey > key) key = okey;
}

// ------- kernel 3: FPS — single barrier, no atomics, prefetched candidate mux -------
__global__ __launch_bounds__(TPB, 1) void k_fps(const int* __restrict__ cnt,
                                                const float4* __restrict__ cxyzd_g,
                                                int* __restrict__ idxsel) {
    int b = blockIdx.x, tid = threadIdx.x;
    int nc = cnt[b];
    if (nc == 0) {  // no graspable points: reference selects index 0 forever
        for (int i = tid; i < MM; i += TPB) idxsel[b * MM + i] = 0;
        return;
    }
    if (nc > CAP) return;  // slow-path kernel handles this

    __shared__ float4 xyzc[CAP];      // 128 KiB: {x,y,z, orig_idx_bits}, read-only in loop
    __shared__ u64 red[2][8];         // double-buffered per-wave keys {mono<<32 | ~p}

    f32x2 px2[NPAIR], py2[NPAIR], pz2[NPAIR];
    float pd[KPT];
    const float4* src = cxyzd_g + (size_t)b * CAP;
#pragma unroll
    for (int j = 0; j < NPAIR; j++) {
        int p0 = (2 * j) * TPB + tid;
        int p1 = (2 * j + 1) * TPB + tid;
        bool v0 = p0 < nc, v1 = p1 < nc;
        float4 a = v0 ? src[p0] : make_float4(0.f, 0.f, 0.f, 0.f);
        float4 c = v1 ? src[p1] : make_float4(0.f, 0.f, 0.f, 0.f);
        px2[j] = (f32x2){a.x, c.x};
        py2[j] = (f32x2){a.y, c.y};
        pz2[j] = (f32x2){a.z, c.z};
        pd[2 * j]     = v0 ? __builtin_inff() : -__builtin_inff();
        pd[2 * j + 1] = v1 ? __builtin_inff() : -__builtin_inff();
        if (v0) xyzc[p0] = a;
        if (v1) xyzc[p1] = c;
    }
    float4 c4 = src[0];   // first center = compacted point 0 (all threads; cached broadcast)
    __syncthreads();

    for (int it = 0; it < MM; it++) {
        if (tid == 0) idxsel[b * MM + it] = __float_as_int(c4.w);  // emit current center
        f32x2 ncx = {-c4.x, -c4.x};
        f32x2 ncy = {-c4.y, -c4.y};
        f32x2 ncz = {-c4.z, -c4.z};

        float bv = -__builtin_inff();
        int bk = 0;
#pragma unroll
        for (int j = 0; j < NPAIR; j++) {
            f32x2 d2, t;
            // exact f32 per half, no contraction: ((dx*dx + dy*dy) + dz*dz)
            asm("v_pk_add_f32 %0, %2, %4\n\t"
                "v_pk_add_f32 %1, %3, %5\n\t"
                "v_pk_mul_f32 %0, %0, %0\n\t"
                "v_pk_mul_f32 %1, %1, %1\n\t"
                "v_pk_add_f32 %0, %0, %1\n\t"
                "v_pk_add_f32 %1, %6, %7\n\t"
                "v_pk_mul_f32 %1, %1, %1\n\t"
                "v_pk_add_f32 %0, %0, %1"
                : "=&v"(d2), "=&v"(t)
                : "v"(px2[j]), "v"(py2[j]), "v"(ncx), "v"(ncy), "v"(pz2[j]), "v"(ncz));
            float nd0 = fminf(pd[2 * j], d2.x);
            float nd1 = fminf(pd[2 * j + 1], d2.y);
            pd[2 * j] = nd0;
            pd[2 * j + 1] = nd1;
            // strict > with ascending k keeps smallest slot on ties
            if (nd0 > bv) { bv = nd0; bk = 2 * j; }
            if (nd1 > bv) { bv = nd1; bk = 2 * j + 1; }
        }

        // monotone f32->u32 map (handles -inf for all-invalid threads)
        unsigned u = (unsigned)__float_as_int(bv);
        unsigned mono = u ^ ((unsigned)(((int)u) >> 31) | 0x80000000u);
        unsigned keylo = ~((unsigned)(bk * TPB + tid));   // ~p
        u64 key = ((u64)mono << 32) | keylo;

        // full 64-lane wave argmax (value desc, compacted idx asc) -> lane 63
        dpp_key_max<0x111, 0xF>(key);  // row_shr:1
        dpp_key_max<0x112, 0xF>(key);  // row_shr:2
        dpp_key_max<0x114, 0xF>(key);  // row_shr:4
        dpp_key_max<0x118, 0xF>(key);  // row_shr:8
        dpp_key_max<0x142, 0xA>(key);  // row_bcast:15 -> rows 1,3
        dpp_key_max<0x143, 0xC>(key);  // row_bcast:31 -> rows 2,3
        if ((tid & 63) == 63) red[it & 1][tid >> 6] = key;
        __syncthreads();   // single barrier: all wave keys published

        // read the 8 wave keys
        const ulonglong2* rp = (const ulonglong2*)red[it & 1];
        ulonglong2 ra = rp[0], rb = rp[1], rc = rp[2], rd = rp[3];
        // prefetch all 8 candidate centers (broadcast LDS reads; overlap tournament)
        float4 d0 = xyzc[(int)(~(unsigned)ra.x)];
        float4 d1 = xyzc[(int)(~(unsigned)ra.y)];
        float4 d2c = xyzc[(int)(~(unsigned)rb.x)];
        float4 d3 = xyzc[(int)(~(unsigned)rb.y)];
        float4 d4 = xyzc[(int)(~(unsigned)rc.x)];
        float4 d5 = xyzc[(int)(~(unsigned)rc.y)];
        float4 d6 = xyzc[(int)(~(unsigned)rd.x)];
        float4 d7 = xyzc[(int)(~(unsigned)rd.y)];
        // 3-level tournament over unique keys
        u64 ka = ra.x; int ia = 0; if (ra.y > ka) { ka = ra.y; ia = 1; }
        u64 kb = rb.x; int ib = 2; if (rb.y > kb) { kb = rb.y; ib = 3; }
        u64 kc = rc.x; int ic = 4; if (rc.y > kc) { kc = rc.y; ic = 5; }
        u64 kd = rd.x; int id = 6; if (rd.y > kd) { kd = rd.y; id = 7; }
        if (kb > ka) { ka = kb; ia = ib; }
        if (kd > kc) { kc = kd; ic = id; }
        if (kc > ka) { ka = kc; ia = ic; }
        // mux winner coords into registers (next center)
        float4 e0, e1, e2, e3, f0, f1;
        e0 = (ia & 1) ? d1 : d0;
        e1 = (ia & 1) ? d3 : d2c;
        e2 = (ia & 1) ? d5 : d4;
        e3 = (ia & 1) ? d7 : d6;
        f0 = (ia & 2) ? e1 : e0;
        f1 = (ia & 2) ? e3 : e2;
        c4 = (ia & 4) ? f1 : f0;
    }
}

// ---------------- kernel 3b: FPS slow path (cnt > CAP; global arrays) ----------------
__global__ __launch_bounds__(1024) void k_fps_slow(const float* __restrict__ pc,
                                                   const unsigned char* __restrict__ mask,
                                                   const int* __restrict__ cnt,
                                                   float* __restrict__ dist,
                                                   int* __restrict__ idxsel) {
    int b = blockIdx.x, tid = threadIdx.x;
    int lane = tid & 63, wv = tid >> 6;
    if (cnt[b] <= CAP) return;
    __shared__ float redv[16];
    __shared__ int   redp[16];
    __shared__ int   bc;
    int firstn = 0x7fffffff;
    for (int n = tid; n < NN; n += 1024) {
        bool m = mask[(size_t)b * NN + n] != 0;
        dist[(size_t)b * NN + n] = m ? __builtin_inff() : -__builtin_inff();
        if (m && firstn == 0x7fffffff) firstn = n;
    }
    for (int off = 32; off >= 1; off >>= 1) {
        int on = __shfl_xor(firstn, off, 64);
        if (on < firstn) firstn = on;
    }
    if (lane == 0) redp[wv] = firstn;
    __syncthreads();
    if (tid < 64) {
        int p2 = (lane < 16) ? redp[lane] : 0x7fffffff;
        for (int off = 8; off >= 1; off >>= 1) {
            int op = __shfl_xor(p2, off, 64);
            if (op < p2) p2 = op;
        }
        if (lane == 0) bc = p2;
    }
    __threadfence_block();
    __syncthreads();
    int last = bc;
    for (int it = 0; it < MM; it++) {
        float cx = pc[((size_t)b * NN + last) * 3 + 0];
        float cy = pc[((size_t)b * NN + last) * 3 + 1];
        float cz = pc[((size_t)b * NN + last) * 3 + 2];
        float bv = -__builtin_inff();
        int bp = 0x7fffffff;
        for (int n = tid; n < NN; n += 1024) {
            float x = pc[((size_t)b * NN + n) * 3 + 0];
            float y = pc[((size_t)b * NN + n) * 3 + 1];
            float z = pc[((size_t)b * NN + n) * 3 + 2];
            float dx = __fsub_rn(x, cx), dy = __fsub_rn(y, cy), dz = __fsub_rn(z, cz);
            float d = __fadd_rn(__fadd_rn(__fmul_rn(dx, dx), __fmul_rn(dy, dy)),
                                __fmul_rn(dz, dz));
            float od = dist[(size_t)b * NN + n];
            float nd = fminf(od, d);
            dist[(size_t)b * NN + n] = nd;
            if (nd > bv) { bv = nd; bp = n; }
        }
        for (int off = 32; off >= 1; off >>= 1) {
            float ov = __shfl_xor(bv, off, 64);
            int   op = __shfl_xor(bp, off, 64);
            if (ov > bv || (ov == bv && op < bp)) { bv = ov; bp = op; }
        }
        if (lane == 0) { redv[wv] = bv; redp[wv] = bp; }
        if (tid == 1023) idxsel[b * MM + it] = last;
        __threadfence_block();
        __syncthreads();
        if (tid < 64) {
            float v2 = (lane < 16) ? redv[lane] : -__builtin_inff();
            int   p2 = (lane < 16) ? redp[lane] : 0x7fffffff;
            for (int off = 8; off >= 1; off >>= 1) {
                float ov = __shfl_xor(v2, off, 64);
                int   op = __shfl_xor(p2, off, 64);
                if (ov > v2 || (ov == v2 && op < p2)) { v2 = ov; p2 = op; }
            }
            if (lane == 0) bc = p2;
        }
        __threadfence_block();
        __syncthreads();
        last = bc;
    }
}

// ---------------- kernel 4: gather + pack [B, 516, 512] ----------------
__global__ __launch_bounds__(256) void k_gather(const float* __restrict__ pc,
                                                const float* __restrict__ feat,
                                                const float* __restrict__ g,
                                                const int* __restrict__ idxsel,
                                                float* __restrict__ out) {
    int bc_ = blockIdx.x;
    int b = bc_ / 516;
    int ch = bc_ % 516;
    for (int m = threadIdx.x; m < MM; m += 256) {
        int n = idxsel[b * MM + m];
        float v;
        if (ch < 512) v = feat[((size_t)b * CC + ch) * NN + n];
        else if (ch < 515) v = pc[((size_t)b * NN + n) * 3 + (ch - 512)];
        else v = g[b * NN + n];
        out[((size_t)b * 516 + ch) * MM + m] = v;
    }
}

extern "C" void kernel_launch(void* const* d_in, const int* in_sizes, int n_in,
                              void* d_out, int out_size, void* d_ws, size_t ws_size,
                              hipStream_t stream) {
    const float* pc    = (const float*)d_in[0];  // [B,N,3]
    const float* feat  = (const float*)d_in[1];  // [B,C,N]
    const float* Wobj  = (const float*)d_in[2];  // [2,C]
    const float* bobj  = (const float*)d_in[3];  // [2]
    const float* Wg    = (const float*)d_in[4];  // [C]
    const float* bg    = (const float*)d_in[5];  // [1]
    float* out = (float*)d_out;

    char* ws = (char*)d_ws;
    float*         g_buf   = (float*)(ws + OFF_G);
    unsigned char* mask    = (unsigned char*)(ws + OFF_MASK);
    int*           cnt     = (int*)(ws + OFF_CNT);
    int*           cidx    = (int*)(ws + OFF_CIDX);
    float4*        cxyzd   = (float4*)(ws + OFF_CXYZD);
    int*           idxsel  = (int*)(ws + OFF_IDXSEL);
    float*         dslow   = (float*)(ws + OFF_DSLOW);

    k_score<<<dim3(NN / 256, BB), 256, 0, stream>>>(feat, Wobj, bobj, Wg, bg, g_buf, mask);
    k_compact<<<BB, 1024, 0, stream>>>(pc, mask, cnt, cidx, cxyzd);
    k_fps<<<BB, TPB, 0, stream>>>(cnt, cxyzd, idxsel);
    k_fps_slow<<<BB, 1024, 0, stream>>>(pc, mask, cnt, dslow, idxsel);
    k_gather<<<BB * 516, 256, 0, stream>>>(pc, feat, g_buf, idxsel, out);
}

// Round 10
// 629.187 us; speedup vs baseline: 1.0966x; 1.0966x over previous
//
#include <hip/hip_runtime.h>
#include <math.h>

#define BB 4
#define NN 32768
#define CC 512
#define MM 512
#define CAP 8192
#define TPB 256
#define KPT (CAP / TPB)    // 32 slots per thread (16 f32x2 pairs per axis)
#define NPAIR (KPT / 2)

typedef float f32x2 __attribute__((ext_vector_type(2)));
typedef unsigned long long u64;

// ---- workspace layout (bytes) ----
#define OFF_G      0
#define OFF_MASK   (OFF_G + BB*NN*4)           // graspness f32
#define OFF_CNT    (OFF_MASK + BB*NN)          // mask u8
#define OFF_CIDX   (OFF_CNT + 256)             // cnt ints (padded)
#define OFF_CXYZD  (OFF_CIDX + BB*CAP*4)       // compacted orig indices
#define OFF_IDXSEL (OFF_CXYZD + BB*CAP*16)     // compacted float4 {x,y,z, idx_bits}
#define OFF_DSLOW  (OFF_IDXSEL + BB*MM*4)      // slow-path dist array
// total = OFF_DSLOW + BB*NN*4 ~= 1.85 MB

// ---------------- kernel 1: scoring heads + mask ----------------
__global__ __launch_bounds__(256) void k_score(const float* __restrict__ feat,
                                               const float* __restrict__ Wobj,
                                               const float* __restrict__ bobj,
                                               const float* __restrict__ Wg,
                                               const float* __restrict__ bg,
                                               float* __restrict__ g_out,
                                               unsigned char* __restrict__ mask_out) {
    __shared__ float w0[CC], w1[CC], wg[CC];
    for (int c = threadIdx.x; c < CC; c += 256) {
        w0[c] = Wobj[c];
        w1[c] = Wobj[CC + c];
        wg[c] = Wg[c];
    }
    __syncthreads();
    int b = blockIdx.y;
    int n = blockIdx.x * 256 + threadIdx.x;
    const float* f = feat + (size_t)b * CC * NN + n;
    double a0 = 0.0, a1 = 0.0, ag = 0.0;
#pragma unroll 8
    for (int c = 0; c < CC; c++) {
        double fv = (double)f[(size_t)c * NN];
        a0 += fv * (double)w0[c];
        a1 += fv * (double)w1[c];
        ag += fv * (double)wg[c];
    }
    float o0 = (float)(a0 + (double)bobj[0]);
    float o1 = (float)(a1 + (double)bobj[1]);
    float g  = (float)(ag + (double)bg[0]);
    g_out[b * NN + n] = g;
    // argmax([o0,o1])==1 requires strict o1>o0 (argmax picks first max)
    mask_out[b * NN + n] = (o1 > o0 && g > 0.1f) ? 1 : 0;
}

// ---------------- kernel 2: stable compaction of masked points ----------------
__global__ __launch_bounds__(1024) void k_compact(const float* __restrict__ pc,
                                                  const unsigned char* __restrict__ mask,
                                                  int* __restrict__ cnt,
                                                  int* __restrict__ cidx,
                                                  float4* __restrict__ cxyzd) {
    int b = blockIdx.x, tid = threadIdx.x;
    int lane = tid & 63, wv = tid >> 6;
    __shared__ int wcnt[16], woff[16];
    __shared__ int base;
    if (tid == 0) base = 0;
    __syncthreads();
    for (int ch = 0; ch < NN / 1024; ch++) {
        int n = ch * 1024 + tid;
        bool m = mask[(size_t)b * NN + n] != 0;
        unsigned long long bal = __ballot(m);
        int before = __popcll(bal & ((1ull << lane) - 1ull));
        if (lane == 0) wcnt[wv] = __popcll(bal);
        __syncthreads();
        if (tid == 0) {
            int r = base;
            for (int w = 0; w < 16; w++) { woff[w] = r; r += wcnt[w]; }
            base = r;
        }
        __syncthreads();
        if (m) {
            int pos = woff[wv] + before;
            if (pos < CAP) {
                cidx[b * CAP + pos] = n;
                const float* p = pc + ((size_t)b * NN + n) * 3;
                cxyzd[b * CAP + pos] = make_float4(p[0], p[1], p[2], __int_as_float(n));
            }
        }
        __syncthreads();
    }
    if (tid == 0) cnt[b] = base;
}

// ---- u64-key DPP pair-max (builtin form: compiler inserts DPP hazard nops) ----
template<int CTRL, int RMASK>
__device__ __forceinline__ void dpp_key_max(u64& key) {
    int lo = (int)(unsigned)key;
    int hi = (int)(unsigned)(key >> 32);
    int olo = __builtin_amdgcn_update_dpp(lo, lo, CTRL, RMASK, 0xF, false);
    int ohi = __builtin_amdgcn_update_dpp(hi, hi, CTRL, RMASK, 0xF, false);
    u64 okey = ((u64)(unsigned)ohi << 32) | (unsigned)olo;
    if (okey > key) key = okey;
}

// ------- kernel 3: FPS — 4 waves (1/SIMD), single barrier, tournament-mux tail -------
__global__ __launch_bounds__(TPB, 1) void k_fps(const int* __restrict__ cnt,
                                                const float4* __restrict__ cxyzd_g,
                                                int* __restrict__ idxsel) {
    int b = blockIdx.x, tid = threadIdx.x;
    int nc = cnt[b];
    if (nc == 0) {  // no graspable points: reference selects index 0 forever
        for (int i = tid; i < MM; i += TPB) idxsel[b * MM + i] = 0;
        return;
    }
    if (nc > CAP) return;  // slow-path kernel handles this

    __shared__ float4 xyzc[CAP];      // 128 KiB: {x,y,z, orig_idx_bits}, read-only in loop
    __shared__ u64 red[2][4];         // double-buffered per-wave keys {mono<<32 | ~p}

    f32x2 px2[NPAIR], py2[NPAIR], pz2[NPAIR];
    float pd[KPT];
    const float4* src = cxyzd_g + (size_t)b * CAP;
#pragma unroll
    for (int j = 0; j < NPAIR; j++) {
        int p0 = (2 * j) * TPB + tid;
        int p1 = (2 * j + 1) * TPB + tid;
        bool v0 = p0 < nc, v1 = p1 < nc;
        float4 a = v0 ? src[p0] : make_float4(0.f, 0.f, 0.f, 0.f);
        float4 c = v1 ? src[p1] : make_float4(0.f, 0.f, 0.f, 0.f);
        px2[j] = (f32x2){a.x, c.x};
        py2[j] = (f32x2){a.y, c.y};
        pz2[j] = (f32x2){a.z, c.z};
        pd[2 * j]     = v0 ? __builtin_inff() : -__builtin_inff();
        pd[2 * j + 1] = v1 ? __builtin_inff() : -__builtin_inff();
        if (v0) xyzc[p0] = a;
        if (v1) xyzc[p1] = c;
    }
    float4 c4 = src[0];   // first center = compacted point 0 (all threads; cached broadcast)
    __syncthreads();

    for (int it = 0; it < MM; it++) {
        if (tid == 0) idxsel[b * MM + it] = __float_as_int(c4.w);  // emit current center
        f32x2 ncx = {-c4.x, -c4.x};
        f32x2 ncy = {-c4.y, -c4.y};
        f32x2 ncz = {-c4.z, -c4.z};

        float bv = -__builtin_inff();
        int bk = 0;
#pragma unroll
        for (int j = 0; j < NPAIR; j++) {
            f32x2 d2, t;
            // exact f32 per half, no contraction: ((dx*dx + dy*dy) + dz*dz)
            asm("v_pk_add_f32 %0, %2, %4\n\t"
                "v_pk_add_f32 %1, %3, %5\n\t"
                "v_pk_mul_f32 %0, %0, %0\n\t"
                "v_pk_mul_f32 %1, %1, %1\n\t"
                "v_pk_add_f32 %0, %0, %1\n\t"
                "v_pk_add_f32 %1, %6, %7\n\t"
                "v_pk_mul_f32 %1, %1, %1\n\t"
                "v_pk_add_f32 %0, %0, %1"
                : "=&v"(d2), "=&v"(t)
                : "v"(px2[j]), "v"(py2[j]), "v"(ncx), "v"(ncy), "v"(pz2[j]), "v"(ncz));
            float nd0 = fminf(pd[2 * j], d2.x);
            float nd1 = fminf(pd[2 * j + 1], d2.y);
            pd[2 * j] = nd0;
            pd[2 * j + 1] = nd1;
            // strict > with ascending k keeps smallest slot on ties
            if (nd0 > bv) { bv = nd0; bk = 2 * j; }
            if (nd1 > bv) { bv = nd1; bk = 2 * j + 1; }
        }

        // monotone f32->u32 map (handles -inf for all-invalid threads)
        unsigned u = (unsigned)__float_as_int(bv);
        unsigned mono = u ^ ((unsigned)(((int)u) >> 31) | 0x80000000u);
        unsigned keylo = ~((unsigned)(bk * TPB + tid));   // ~p
        u64 key = ((u64)mono << 32) | keylo;

        // full 64-lane wave argmax (value desc, compacted idx asc) -> lane 63
        dpp_key_max<0x111, 0xF>(key);  // row_shr:1
        dpp_key_max<0x112, 0xF>(key);  // row_shr:2
        dpp_key_max<0x114, 0xF>(key);  // row_shr:4
        dpp_key_max<0x118, 0xF>(key);  // row_shr:8
        dpp_key_max<0x142, 0xA>(key);  // row_bcast:15 -> rows 1,3
        dpp_key_max<0x143, 0xC>(key);  // row_bcast:31 -> rows 2,3
        if ((tid & 63) == 63) red[it & 1][tid >> 6] = key;
        __syncthreads();   // single barrier: all wave keys published

        // read the 4 wave keys
        const ulonglong2* rp = (const ulonglong2*)red[it & 1];
        ulonglong2 ra = rp[0], rb = rp[1];
        // prefetch all 4 candidate centers (broadcast LDS reads; overlap tournament)
        float4 d0 = xyzc[(int)(~(unsigned)ra.x)];
        float4 d1 = xyzc[(int)(~(unsigned)ra.y)];
        float4 d2c = xyzc[(int)(~(unsigned)rb.x)];
        float4 d3 = xyzc[(int)(~(unsigned)rb.y)];
        // 2-level tournament over unique keys
        u64 ka = ra.x; int ia = 0; if (ra.y > ka) { ka = ra.y; ia = 1; }
        u64 kb = rb.x; int ib = 2; if (rb.y > kb) { kb = rb.y; ib = 3; }
        if (kb > ka) { ka = kb; ia = ib; }
        // mux winner coords into registers (next center)
        float4 e0 = (ia & 1) ? d1 : d0;
        float4 e1 = (ia & 1) ? d3 : d2c;
        c4 = (ia & 2) ? e1 : e0;
    }
}

// ---------------- kernel 3b: FPS slow path (cnt > CAP; global arrays) ----------------
__global__ __launch_bounds__(1024) void k_fps_slow(const float* __restrict__ pc,
                                                   const unsigned char* __restrict__ mask,
                                                   const int* __restrict__ cnt,
                                                   float* __restrict__ dist,
                                                   int* __restrict__ idxsel) {
    int b = blockIdx.x, tid = threadIdx.x;
    int lane = tid & 63, wv = tid >> 6;
    if (cnt[b] <= CAP) return;
    __shared__ float redv[16];
    __shared__ int   redp[16];
    __shared__ int   bc;
    int firstn = 0x7fffffff;
    for (int n = tid; n < NN; n += 1024) {
        bool m = mask[(size_t)b * NN + n] != 0;
        dist[(size_t)b * NN + n] = m ? __builtin_inff() : -__builtin_inff();
        if (m && firstn == 0x7fffffff) firstn = n;
    }
    for (int off = 32; off >= 1; off >>= 1) {
        int on = __shfl_xor(firstn, off, 64);
        if (on < firstn) firstn = on;
    }
    if (lane == 0) redp[wv] = firstn;
    __syncthreads();
    if (tid < 64) {
        int p2 = (lane < 16) ? redp[lane] : 0x7fffffff;
        for (int off = 8; off >= 1; off >>= 1) {
            int op = __shfl_xor(p2, off, 64);
            if (op < p2) p2 = op;
        }
        if (lane == 0) bc = p2;
    }
    __threadfence_block();
    __syncthreads();
    int last = bc;
    for (int it = 0; it < MM; it++) {
        float cx = pc[((size_t)b * NN + last) * 3 + 0];
        float cy = pc[((size_t)b * NN + last) * 3 + 1];
        float cz = pc[((size_t)b * NN + last) * 3 + 2];
        float bv = -__builtin_inff();
        int bp = 0x7fffffff;
        for (int n = tid; n < NN; n += 1024) {
            float x = pc[((size_t)b * NN + n) * 3 + 0];
            float y = pc[((size_t)b * NN + n) * 3 + 1];
            float z = pc[((size_t)b * NN + n) * 3 + 2];
            float dx = __fsub_rn(x, cx), dy = __fsub_rn(y, cy), dz = __fsub_rn(z, cz);
            float d = __fadd_rn(__fadd_rn(__fmul_rn(dx, dx), __fmul_rn(dy, dy)),
                                __fmul_rn(dz, dz));
            float od = dist[(size_t)b * NN + n];
            float nd = fminf(od, d);
            dist[(size_t)b * NN + n] = nd;
            if (nd > bv) { bv = nd; bp = n; }
        }
        for (int off = 32; off >= 1; off >>= 1) {
            float ov = __shfl_xor(bv, off, 64);
            int   op = __shfl_xor(bp, off, 64);
            if (ov > bv || (ov == bv && op < bp)) { bv = ov; bp = op; }
        }
        if (lane == 0) { redv[wv] = bv; redp[wv] = bp; }
        if (tid == 1023) idxsel[b * MM + it] = last;
        __threadfence_block();
        __syncthreads();
        if (tid < 64) {
            float v2 = (lane < 16) ? redv[lane] : -__builtin_inff();
            int   p2 = (lane < 16) ? redp[lane] : 0x7fffffff;
            for (int off = 8; off >= 1; off >>= 1) {
                float ov = __shfl_xor(v2, off, 64);
                int   op = __shfl_xor(p2, off, 64);
                if (ov > v2 || (ov == v2 && op < p2)) { v2 = ov; p2 = op; }
            }
            if (lane == 0) bc = p2;
        }
        __threadfence_block();
        __syncthreads();
        last = bc;
    }
}

// ---------------- kernel 4: gather + pack [B, 516, 512] ----------------
__global__ __launch_bounds__(256) void k_gather(const float* __restrict__ pc,
                                                const float* __restrict__ feat,
                                                const float* __restrict__ g,
                                                const int* __restrict__ idxsel,
                                                float* __restrict__ out) {
    int bc_ = blockIdx.x;
    int b = bc_ / 516;
    int ch = bc_ % 516;
    for (int m = threadIdx.x; m < MM; m += 256) {
        int n = idxsel[b * MM + m];
        float v;
        if (ch < 512) v = feat[((size_t)b * CC + ch) * NN + n];
        else if (ch < 515) v = pc[((size_t)b * NN + n) * 3 + (ch - 512)];
        else v = g[b * NN + n];
        out[((size_t)b * 516 + ch) * MM + m] = v;
    }
}

extern "C" void kernel_launch(void* const* d_in, const int* in_sizes, int n_in,
                              void* d_out, int out_size, void* d_ws, size_t ws_size,
                              hipStream_t stream) {
    const float* pc    = (const float*)d_in[0];  // [B,N,3]
    const float* feat  = (const float*)d_in[1];  // [B,C,N]
    const float* Wobj  = (const float*)d_in[2];  // [2,C]
    const float* bobj  = (const float*)d_in[3];  // [2]
    const float* Wg    = (const float*)d_in[4];  // [C]
    const float* bg    = (const float*)d_in[5];  // [1]
    float* out = (float*)d_out;

    char* ws = (char*)d_ws;
    float*         g_buf   = (float*)(ws + OFF_G);
    unsigned char* mask    = (unsigned char*)(ws + OFF_MASK);
    int*           cnt     = (int*)(ws + OFF_CNT);
    int*           cidx    = (int*)(ws + OFF_CIDX);
    float4*        cxyzd   = (float4*)(ws + OFF_CXYZD);
    int*           idxsel  = (int*)(ws + OFF_IDXSEL);
    float*         dslow   = (float*)(ws + OFF_DSLOW);

    k_score<<<dim3(NN / 256, BB), 256, 0, stream>>>(feat, Wobj, bobj, Wg, bg, g_buf, mask);
    k_compact<<<BB, 1024, 0, stream>>>(pc, mask, cnt, cidx, cxyzd);
    k_fps<<<BB, TPB, 0, stream>>>(cnt, cxyzd, idxsel);
    k_fps_slow<<<BB, 1024, 0, stream>>>(pc, mask, cnt, dslow, idxsel);
    k_gather<<<BB * 516, 256, 0, stream>>>(pc, feat, g_buf, idxsel, out);
}